// Round 3
// baseline (290.530 us; speedup 1.0000x reference)
//
#include <hip/hip_runtime.h>

#define OUT_F 11008
#define IN_F  4096
#define NBATCH 8
#define R 4                      // output rows per wave
#define BLOCK 64                 // one wave per block
#define NGR 32                   // groups per row = IN_F/128
#define KITERS (IN_F / (4 * BLOCK))   // 16 iters: lane covers 4 cols per iter

#define NWORDS (OUT_F * IN_F / 4)     // 11,272,192 ushorts, 4 nibbles each
#define PK_WPB 1024                   // words per block -> grid 11008, exact
#define PK_THREADS 256

// ext_vector aliases
typedef int   vint4   __attribute__((ext_vector_type(4)));
typedef float vfloat4 __attribute__((ext_vector_type(4)));

// R15: isolate the stream mechanics. R14's pack (nt loads, grid-stride with
// runtime trip count -> 1 load in flight between vmcnt waits) hit the same
// 2.4 TB/s as every fused variant (bench math: pack ~84us on 203MB).
// Hypothesis: the cap is issue-window depth (+ nt L2-bypass latency), not
// the widx buffer. This pack is the m13 shape: normal cached loads,
// exact one-shot grid (11008x256, 4 words/thread), compile-time unroll ->
// 4 independent dwordx4 in flight per wave, instruction-contiguous 4KB per
// wave-instr, full occupancy (32 waves/CU -> ~128KB/CU outstanding).

__global__ __launch_bounds__(PK_THREADS) void pack_kernel(
    const int* __restrict__ widx,            // [45,088,768] in [0,16)
    unsigned short* __restrict__ packed)     // [11,272,192] 4 nibbles each
{
    const size_t base = (size_t)blockIdx.x * PK_WPB;
    const int tid = threadIdx.x;
    const vint4* __restrict__ src = reinterpret_cast<const vint4*>(widx);

    vint4 v[4];
#pragma unroll
    for (int j = 0; j < 4; ++j)
        v[j] = src[base + j * PK_THREADS + tid];   // 4 independent loads in flight

#pragma unroll
    for (int j = 0; j < 4; ++j)
        packed[base + j * PK_THREADS + tid] = (unsigned short)(
            (v[j].x & 0xF) | ((v[j].y & 0xF) << 4) |
            ((v[j].z & 0xF) << 8) | ((v[j].w & 0xF) << 12));
}

__global__ __launch_bounds__(BLOCK) void pal_linear_kernel(
    const float* __restrict__ x,             // [8, 4096]
    const unsigned short* __restrict__ pidx, // [OUT_F * 1024] packed nibbles
    const float* __restrict__ lut,           // [352256, 16] f32 on device
    const float* __restrict__ bias,          // [11008]
    float* __restrict__ out)                 // [8, 11008]
{
    __shared__ float lutS[R * NGR * 16];     // 8 KB wave-private slice

    const int tid = threadIdx.x;             // lane 0..63
    const int o0  = blockIdx.x * R;

    // stage the tile's LUT slice (nt: read-once stream)
    {
        const vfloat4* src = reinterpret_cast<const vfloat4*>(lut + (size_t)o0 * NGR * 16);
        float4* dst = reinterpret_cast<float4*>(lutS);
#pragma unroll
        for (int i = 0; i < (R * NGR * 16 / 4) / BLOCK; ++i) {   // 8 iters
            const vfloat4 v = __builtin_nontemporal_load(src + tid + i * BLOCK);
            dst[tid + i * BLOCK] = make_float4(v.x, v.y, v.z, v.w);
        }
    }
    __syncthreads();

    float acc[R][NBATCH];
#pragma unroll
    for (int r = 0; r < R; ++r)
#pragma unroll
        for (int m = 0; m < NBATCH; ++m) acc[r][m] = 0.0f;

    // 1-deep prefetch, ushort per row = 8 VGPRs total for both buffers
    unsigned short icur[R], inxt[R];
#pragma unroll
    for (int r = 0; r < R; ++r)
        icur[r] = pidx[(size_t)(o0 + r) * (IN_F / 4) + tid];

#pragma unroll 1
    for (int k = 0; k < KITERS; ++k) {
        const int c = 4 * (tid + BLOCK * k);

        // 1) x loads (L2-hot — x IS reused across blocks)
        float4 xv[NBATCH];
#pragma unroll
        for (int m = 0; m < NBATCH; ++m)
            xv[m] = *reinterpret_cast<const float4*>(x + m * IN_F + c);

        // 2) idx prefetch (coalesced, mostly L2/L3-hot from pack's stores)
        if (k + 1 < KITERS) {
#pragma unroll
            for (int r = 0; r < R; ++r)
                inxt[r] = pidx[(size_t)(o0 + r) * (IN_F / 4) + tid + BLOCK * (k + 1)];
        }

        // 3) LDS gathers with current indices (4 nibbles per row)
        const int gcol = (c >> 7) * 16;
        float w[R][4];
#pragma unroll
        for (int r = 0; r < R; ++r) {
            const float* lr = lutS + r * (NGR * 16) + gcol;
            const unsigned int u = icur[r];
            w[r][0] = lr[u & 0xF];
            w[r][1] = lr[(u >> 4) & 0xF];
            w[r][2] = lr[(u >> 8) & 0xF];
            w[r][3] = lr[(u >> 12) & 0xF];
        }

        // 4) FMAs (fully unrolled, all register-resident)
#pragma unroll
        for (int m = 0; m < NBATCH; ++m)
#pragma unroll
            for (int r = 0; r < R; ++r) {
                float a = acc[r][m];
                a = fmaf(w[r][0], xv[m].x, a);
                a = fmaf(w[r][1], xv[m].y, a);
                a = fmaf(w[r][2], xv[m].z, a);
                a = fmaf(w[r][3], xv[m].w, a);
                acc[r][m] = a;
            }

#pragma unroll
        for (int r = 0; r < R; ++r) icur[r] = inxt[r];
    }

    // full-wave butterfly reduce
#pragma unroll
    for (int r = 0; r < R; ++r)
#pragma unroll
        for (int m = 0; m < NBATCH; ++m) {
            float v = acc[r][m];
#pragma unroll
            for (int off = 32; off >= 1; off >>= 1)
                v += __shfl_xor(v, off, 64);
            acc[r][m] = v;
        }

    // static select (R5 lesson: no runtime indexing of register arrays)
    float v = 0.0f;
#pragma unroll
    for (int r = 0; r < R; ++r)
#pragma unroll
        for (int m = 0; m < NBATCH; ++m)
            if (tid == r * NBATCH + m) v = acc[r][m];

    if (tid < R * NBATCH) {
        const int r = tid >> 3;
        const int m = tid & 7;
        out[(size_t)m * OUT_F + (o0 + r)] = v + bias[o0 + r];
    }
}

extern "C" void kernel_launch(void* const* d_in, const int* in_sizes, int n_in,
                              void* d_out, int out_size, void* d_ws, size_t ws_size,
                              hipStream_t stream) {
    const float* x    = (const float*)d_in[0];
    const int*   widx = (const int*)d_in[1];
    const float* lut  = (const float*)d_in[2];
    const float* bias = (const float*)d_in[3];
    float* out = (float*)d_out;
    unsigned short* packed = (unsigned short*)d_ws;   // 22.5 MB of workspace

    pack_kernel<<<NWORDS / PK_WPB, PK_THREADS, 0, stream>>>(widx, packed);
    pal_linear_kernel<<<OUT_F / R, BLOCK, 0, stream>>>(x, packed, lut, bias, out);
}

// Round 4
// 256.831 us; speedup vs baseline: 1.1312x; 1.1312x over previous
//
#include <hip/hip_runtime.h>

#define OUT_F 11008
#define IN_F  4096
#define NBATCH 8
#define R 4                      // output rows per wave
#define BLOCK 64                 // one wave per block
#define NGR 32                   // groups per row = IN_F/128
#define KITERS (IN_F / (4 * BLOCK))   // 16 iters: lane covers 4 cols per iter

// ext_vector aliases
typedef int   vint4   __attribute__((ext_vector_type(4)));
typedef float vfloat4 __attribute__((ext_vector_type(4)));

// R16: fused 79us structure + system-scope non-temporal widx loads.
// Theory C': FETCH/WRITE_SIZE are TCC(L2) counters and can't see MALL<->HBM.
// The 721MB poison fill leaves the 256MB Infinity Cache full of DIRTY d_ws
// lines; every cold read miss then evicts a dirty line -> hidden HBM
// writeback. 225MB reads + ~256MB writebacks ~= 480MB @6.5TB/s = 74us ~=
// the measured 79us. Plain `nt` (R0, neutral) only reaches L2; `sc0 sc1 nt`
// = system-scope non-temporal is the strongest no-allocate encoding.
// If reads skip MALL allocation, dirty lines stay put (next fill re-dirties
// them in place, no writeback) -> pure 225MB read ~= 35-40us kernel.
// R15 killed the issue-depth theory: full-occupancy 4-deep cached stream
// still ~2.2 TB/s apparent. Split kernels strictly worse; back to fused.

__device__ __forceinline__ vint4 load_idx_stream(const int* p) {
    vint4 r;
    asm volatile("global_load_dwordx4 %0, %1, off sc0 sc1 nt"
                 : "=v"(r) : "v"(p));
    return r;
}

__global__ __launch_bounds__(BLOCK) void pal_linear_kernel(
    const float* __restrict__ x,        // [8, 4096]
    const int*   __restrict__ widx,     // [11008*4096] in [0,16)
    const float* __restrict__ lut,      // [352256, 16] f32 on device
    const float* __restrict__ bias,     // [11008]
    float* __restrict__ out)            // [8, 11008]
{
    __shared__ float lutS[R * NGR * 16];   // 8 KB wave-private slice

    const int tid = threadIdx.x;           // lane 0..63
    const int o0  = blockIdx.x * R;

    // stage the tile's LUT slice (nt builtin; 10% of traffic, keep simple)
    {
        const vfloat4* src = reinterpret_cast<const vfloat4*>(lut + (size_t)o0 * NGR * 16);
        float4* dst = reinterpret_cast<float4*>(lutS);
#pragma unroll
        for (int i = 0; i < (R * NGR * 16 / 4) / BLOCK; ++i) {   // 8 iters
            const vfloat4 v = __builtin_nontemporal_load(src + tid + i * BLOCK);
            dst[tid + i * BLOCK] = make_float4(v.x, v.y, v.z, v.w);
        }
    }
    __syncthreads();

    float acc[R][NBATCH];
#pragma unroll
    for (int r = 0; r < R; ++r)
#pragma unroll
        for (int m = 0; m < NBATCH; ++m) acc[r][m] = 0.0f;

    vint4 idx_cur[R], idx_nxt[R];
#pragma unroll
    for (int r = 0; r < R; ++r)
        idx_cur[r] = load_idx_stream(widx + (size_t)(o0 + r) * IN_F + 4 * tid);
    // drain the 4 initial idx loads before first use (rule #18 pattern)
    asm volatile("s_waitcnt vmcnt(0)" ::: "memory");
    __builtin_amdgcn_sched_barrier(0);

#pragma unroll 1
    for (int k = 0; k < KITERS; ++k) {
        const int c = 4 * (tid + BLOCK * k);

        // 1) x loads (L2-hot, cached normally — x IS reused across blocks)
        float4 xv[NBATCH];
#pragma unroll
        for (int m = 0; m < NBATCH; ++m)
            xv[m] = *reinterpret_cast<const float4*>(x + m * IN_F + c);

        // 2) idx prefetch for k+1 — system-scope nt, no MALL allocate
        if (k + 1 < KITERS) {
#pragma unroll
            for (int r = 0; r < R; ++r)
                idx_nxt[r] = load_idx_stream(
                    widx + (size_t)(o0 + r) * IN_F + c + 4 * BLOCK);
        }

        // 3) LDS gathers with current indices
        const int gcol = (c >> 7) * 16;
        float w[R][4];
#pragma unroll
        for (int r = 0; r < R; ++r) {
            const float* lr = lutS + r * (NGR * 16) + gcol;
            w[r][0] = lr[idx_cur[r].x];
            w[r][1] = lr[idx_cur[r].y];
            w[r][2] = lr[idx_cur[r].z];
            w[r][3] = lr[idx_cur[r].w];
        }

        // 4) FMAs (fully unrolled, all register-resident)
#pragma unroll
        for (int m = 0; m < NBATCH; ++m)
#pragma unroll
            for (int r = 0; r < R; ++r) {
                float a = acc[r][m];
                a = fmaf(w[r][0], xv[m].x, a);
                a = fmaf(w[r][1], xv[m].y, a);
                a = fmaf(w[r][2], xv[m].z, a);
                a = fmaf(w[r][3], xv[m].w, a);
                acc[r][m] = a;
            }

        // wait for prefetch (overlapped with the gathers+FMAs above),
        // then rotate buffers. sched_barrier: nothing moves above the wait.
        asm volatile("s_waitcnt vmcnt(0)" ::: "memory");
        __builtin_amdgcn_sched_barrier(0);
#pragma unroll
        for (int r = 0; r < R; ++r) idx_cur[r] = idx_nxt[r];
    }

    // full-wave butterfly reduce
#pragma unroll
    for (int r = 0; r < R; ++r)
#pragma unroll
        for (int m = 0; m < NBATCH; ++m) {
            float v = acc[r][m];
#pragma unroll
            for (int off = 32; off >= 1; off >>= 1)
                v += __shfl_xor(v, off, 64);
            acc[r][m] = v;
        }

    // static select (R5 lesson: no runtime indexing of register arrays)
    float v = 0.0f;
#pragma unroll
    for (int r = 0; r < R; ++r)
#pragma unroll
        for (int m = 0; m < NBATCH; ++m)
            if (tid == r * NBATCH + m) v = acc[r][m];

    if (tid < R * NBATCH) {
        const int r = tid >> 3;
        const int m = tid & 7;
        out[(size_t)m * OUT_F + (o0 + r)] = v + bias[o0 + r];
    }
}

extern "C" void kernel_launch(void* const* d_in, const int* in_sizes, int n_in,
                              void* d_out, int out_size, void* d_ws, size_t ws_size,
                              hipStream_t stream) {
    const float* x    = (const float*)d_in[0];
    const int*   widx = (const int*)d_in[1];
    const float* lut  = (const float*)d_in[2];
    const float* bias = (const float*)d_in[3];
    float* out = (float*)d_out;

    pal_linear_kernel<<<OUT_F / R, BLOCK, 0, stream>>>(x, widx, lut, bias, out);
}